// Round 5
// baseline (1877.094 us; speedup 1.0000x reference)
//
#include <hip/hip_runtime.h>
#include <stdint.h>

// Problem constants
#define B_SZ 32
#define SEQ  512
#define DIM  768
#define NH   12
#define HD   64
#define ROWS (B_SZ*SEQ)   // 16384

typedef __attribute__((ext_vector_type(4))) float f32x4;
typedef __attribute__((ext_vector_type(8))) _Float16 half8;

// async global->LDS, 16B per lane; LDS dest = wave-uniform base + lane*16
// (global address is per-lane arbitrary -> XOR-swizzled fetches are legal)
#define GLOAD_LDS16(gaddr, laddr) \
  __builtin_amdgcn_global_load_lds((const __attribute__((address_space(1))) void*)(gaddr), \
                                   (__attribute__((address_space(3))) void*)(laddr), 16, 0, 0)

__device__ __forceinline__ unsigned short h2u(_Float16 h){
  union { _Float16 h; unsigned short u; } c; c.h = h; return c.u;
}
__device__ __forceinline__ unsigned short f2hu(float f){
  return h2u((_Float16)f);
}

// ---------------- prep kernels ----------------
// x fp32 -> fp16 hi + fp16 lo residual, 4 elems/thread
__global__ void k_split(const float* __restrict__ x,
                        unsigned short* __restrict__ xh,
                        unsigned short* __restrict__ xl, int n4){
  int i = blockIdx.x * 256 + threadIdx.x;
  if (i >= n4) return;
  float4 v = ((const float4*)x)[i];
  ushort4 h, l;
  _Float16 t;
  t = (_Float16)v.x; h.x = h2u(t); l.x = f2hu(v.x - (float)t);
  t = (_Float16)v.y; h.y = h2u(t); l.y = f2hu(v.y - (float)t);
  t = (_Float16)v.z; h.z = h2u(t); l.z = f2hu(v.z - (float)t);
  t = (_Float16)v.w; h.w = h2u(t); l.w = f2hu(v.w - (float)t);
  ((ushort4*)xh)[i] = h;
  ((ushort4*)xl)[i] = l;
}

// QT[h][e][d] = split(Q[h][d][e]) — LDS-tiled transpose, both sides coalesced
__global__ __launch_bounds__(256) void k_transQ(const float* __restrict__ Q,
                         unsigned short* __restrict__ qth,
                         unsigned short* __restrict__ qtl){
  __shared__ float tile[32][33];
  int h = blockIdx.z;
  int d0 = blockIdx.x * 32;
  int e0 = blockIdx.y * 32;
  int tx = threadIdx.x & 31, ty = threadIdx.x >> 5;  // 32 x 8
  const float* Qh = Q + (size_t)h * DIM * DIM;
  for (int i = 0; i < 4; ++i)
    tile[ty + i*8][tx] = Qh[(size_t)(d0 + ty + i*8) * DIM + e0 + tx];
  __syncthreads();
  for (int i = 0; i < 4; ++i){
    float v = tile[tx][ty + i*8];
    size_t o = ((size_t)h * DIM + e0 + ty + i*8) * DIM + d0 + tx;
    _Float16 hi = (_Float16)v;
    qth[o] = h2u(hi);
    qtl[o] = f2hu(v - (float)hi);
  }
}

// Vt[h][e][d] = fp16(V[h][d][e]) — LDS-tiled transpose
__global__ __launch_bounds__(256) void k_transV(const float* __restrict__ V,
                         unsigned short* __restrict__ vt16){
  __shared__ float tile[32][33];
  int h = blockIdx.z;
  int d0 = blockIdx.x * 32;
  int e0 = blockIdx.y * 32;
  int tx = threadIdx.x & 31, ty = threadIdx.x >> 5;
  const float* Vh = V + (size_t)h * DIM * HD;
  for (int i = 0; i < 4; ++i)
    tile[ty + i*8][tx] = Vh[(size_t)(d0 + ty + i*8) * HD + e0 + tx];
  __syncthreads();
  for (int i = 0; i < 4; ++i)
    vt16[((size_t)h * HD + e0 + ty + i*8) * DIM + d0 + tx] = f2hu(tile[tx][ty + i*8]);
}

// ---------------- xV GEMM (round-0 proven: fp16 single-pass, BK=32) ----------------
// xvT[(b*NH+h)*64 + e][n] = sum_d x[b,n,d] * V[h,d,e]
// grid: (4 mtiles, 32 b, 12 h), block 256. tile 128n x 64e.
__global__ __launch_bounds__(256) void k_gemm_xv(
    const unsigned short* __restrict__ xh,
    const unsigned short* __restrict__ vt16,
    unsigned short* __restrict__ xvT){
  __shared__ __align__(16) unsigned short lA[128*32];
  __shared__ __align__(16) unsigned short lB[64*32];
  __shared__ __align__(16) unsigned short lOut[64*128];
  int t = threadIdx.x, w = t >> 6, l = t & 63;
  int lane16 = l & 15, quad = l >> 4;
  int b = blockIdx.y, h = blockIdx.z;
  int m0 = blockIdx.x * 128;
  const unsigned short* vth = vt16 + (size_t)h * HD * DIM;
  f32x4 acc[2][4];
  for (int i = 0; i < 2; ++i) for (int j = 0; j < 4; ++j)
    for (int z = 0; z < 4; ++z) acc[i][j][z] = 0.f;

  for (int kt = 0; kt < DIM/32; ++kt){
    int k0 = kt * 32;
    __syncthreads();
    for (int rep = 0; rep < 2; ++rep){
      int id = t + rep * 256;              // 0..511
      int row = id >> 2, ko = (id & 3) * 8;
      GLOAD_LDS16(&xh[((size_t)(b*SEQ + m0 + row))*DIM + k0 + ko],
                  &lA[(rep*256 + w*64) * 8]);
    }
    { int row = t >> 2, ko = (t & 3) * 8;  // 64x32
      GLOAD_LDS16(&vth[(size_t)row*DIM + k0 + ko], &lB[(w*64) * 8]); }
    __syncthreads();
    half8 a[2];
    for (int i = 0; i < 2; ++i)
      a[i] = *(const half8*)&lA[(w*32 + i*16 + lane16)*32 + quad*8];
    for (int j = 0; j < 4; ++j){
      half8 bb = *(const half8*)&lB[(j*16 + lane16)*32 + quad*8];
      for (int i = 0; i < 2; ++i)
        acc[i][j] = __builtin_amdgcn_mfma_f32_16x16x32_f16(a[i], bb, acc[i][j], 0, 0, 0);
    }
  }
  // epilogue: transpose through LDS, contiguous row stores
  __syncthreads();
  for (int i = 0; i < 2; ++i) for (int j = 0; j < 4; ++j) for (int r = 0; r < 4; ++r){
    int col = j*16 + lane16;
    int n  = w*32 + i*16 + quad*4 + r;
    lOut[col*128 + n] = f2hu(acc[i][j][r]);
  }
  __syncthreads();
  for (int rep = 0; rep < 4; ++rep){
    int id = t + rep*256;                  // 0..1023 int4s
    int e = id >> 4, no = (id & 15) * 8;
    *(int4*)&xvT[((size_t)(b*NH + h)*HD + e)*SEQ + m0 + no] = *(const int4*)&lOut[e*128 + no];
  }
}

// ---------------- q projection (r3-proven structure, merged-N) ----------------
// q[bn][col] = sum_d x[bn][d] * Qflat[col][d], col in [0, ncols); Qflat = qth+h0 slab
// (qth layout [h][e][d] IS a flat [NH*768][768] row-major matrix).
// grid (128 Mtiles, ncols/128 Ntiles), block 256. tile 128x128, BK=64, 64 KB LDS
// -> 2 blocks/CU. LDS rows = 64 shorts (128 B); chunk c (16 B) of row r at slot
// c^(r&7) -> fragment reads bank-balanced. Single-buffered 2-barrier loop: this
// structure's ceiling is ~40% MfmaUtil (r3=194.7us/launch); dbuf (r2), 4-block
// occupancy (r4) both measured null-to-regressive. Do not re-attempt; the only
// path past is the full 8-phase interleave (not a graft).
__global__ __launch_bounds__(256, 2) void k_gemm_q(
    const unsigned short* __restrict__ xh, const unsigned short* __restrict__ xl,
    const unsigned short* __restrict__ bth, const unsigned short* __restrict__ btl,
    unsigned short* __restrict__ qh, unsigned short* __restrict__ ql, int ncols){
  __shared__ __align__(16) unsigned short lA[2][128*64];   // [hl] 32 KB
  __shared__ __align__(16) unsigned short lB[2][128*64];   // [hl] 32 KB
  int t = threadIdx.x, w = t >> 6, l = t & 63;
  int lane16 = l & 15, quad = l >> 4;
  int m0 = blockIdx.x * 128, n0 = blockIdx.y * 128;
  int wr = (w >> 1) * 64, wc = (w & 1) * 64;
  f32x4 acc[4][4];
  for (int i = 0; i < 4; ++i) for (int j = 0; j < 4; ++j)
    for (int z = 0; z < 4; ++z) acc[i][j][z] = 0.f;

  for (int kt = 0; kt < DIM/64; ++kt){
    int k0 = kt * 64;
    __syncthreads();                       // previous compute's LDS reads done
    for (int rep = 0; rep < 4; ++rep){
      int id = t + rep * 256;              // 0..1023 (row, chunk)
      int row = id >> 3;
      int gc  = (id & 7) ^ (row & 7);      // fetch swizzled chunk into linear slot
      int lb  = (rep*256 + w*64) * 8;
      size_t gA = (size_t)(m0+row)*DIM + k0 + gc*8;
      size_t gB = (size_t)(n0+row)*DIM + k0 + gc*8;
      GLOAD_LDS16(&xh [gA], &lA[0][lb]);
      GLOAD_LDS16(&xl [gA], &lA[1][lb]);
      GLOAD_LDS16(&bth[gB], &lB[0][lb]);
      GLOAD_LDS16(&btl[gB], &lB[1][lb]);
    }
    __syncthreads();                       // drain staging
    for (int ks = 0; ks < 2; ++ks){
      int sw = ((ks*4 + quad) ^ (lane16 & 7)) * 8;   // swizzled chunk offset
      half8 aH[4], aL[4];
      for (int i = 0; i < 4; ++i){
        int r = wr + i*16 + lane16;
        aH[i] = *(const half8*)&lA[0][r*64 + sw];
        aL[i] = *(const half8*)&lA[1][r*64 + sw];
      }
      for (int j = 0; j < 4; ++j){
        int c = wc + j*16 + lane16;
        half8 bH = *(const half8*)&lB[0][c*64 + sw];
        half8 bL = *(const half8*)&lB[1][c*64 + sw];
        for (int i = 0; i < 4; ++i){
          acc[i][j] = __builtin_amdgcn_mfma_f32_16x16x32_f16(aL[i], bH, acc[i][j], 0, 0, 0);
          acc[i][j] = __builtin_amdgcn_mfma_f32_16x16x32_f16(aH[i], bL, acc[i][j], 0, 0, 0);
          acc[i][j] = __builtin_amdgcn_mfma_f32_16x16x32_f16(aH[i], bH, acc[i][j], 0, 0, 0);
        }
      }
    }
  }
  for (int i = 0; i < 4; ++i) for (int j = 0; j < 4; ++j) for (int r = 0; r < 4; ++r){
    int row = m0 + wr + i*16 + quad*4 + r;
    int col = n0 + wc + j*16 + lane16;
    float v = acc[i][j][r];
    _Float16 hh = (_Float16)v;
    size_t o = (size_t)row*ncols + col;
    qh[o] = h2u(hh);
    ql[o] = f2hu(v - (float)hh);
  }
}

// ---------------- fused attention, merged heads, BARRIER-FREE phase 1 ----------------
// grid (8*hc x-combos, 32 b). block 512 (8 waves, 2/SIMD). BM=64 q-rows, 512 keys.
// Phase 1 has NO block barrier: wave w owns keys [64w,64w+64) and stages them into a
// PER-WAVE private dbuf (8 KB/wave/buf), synced by the wave's OWN counted vmcnt —
// the 8 waves run as independent pipelines (no convoy on a shared vmcnt(0) drain).
// q fragments come straight from global (L2-resident panel, identical addrs across
// waves), double-buffered in registers, prefetched one K-step ahead.
// Ordering is pinned by asm fences: "s_waitcnt vmcnt(8)" w/ memory clobber at each
// half-body top (in-order retirement => own stage(kt) landed; the 8 allowed
// outstanding are the newer q-loads, which the compiler reg-dep waits); an empty
// memory-clobber asm between stageK and loadQ pins DMA-before-q issue order so the
// count is exact. Keys buffers are wave-private => no cross-wave hazard exists.
// LDS pool (shorts): keys[bb][w]: bb*32768 + w*4096 (128 KB, dead after phase 1);
//   phase 2/3 alias: lP rows 64 stride 520 @0; lXv @34816; red float[32768] @0.
#define SEQP 520
__global__ __launch_bounds__(512) void k_attn(
    const unsigned short* __restrict__ qh, const unsigned short* __restrict__ ql,
    const unsigned short* __restrict__ xh, const unsigned short* __restrict__ xl,
    const unsigned short* __restrict__ xvT,
    float* __restrict__ out, int h0, int hc){
  __shared__ __align__(16) unsigned short lsh[73728];   // 144 KB
  __shared__ float lStat[8*64 + 64 + 64];               // 2.5 KB

  int t = threadIdx.x, w = t >> 6, l = t & 63;
  int lane16 = l & 15, quad = l >> 4;
  int bx = blockIdx.x, b = blockIdx.y;
  int hIdx = bx % hc, nt = bx / hc;
  int h = h0 + hIdx;
  int qstride = hc * DIM;
  size_t qoff = (size_t)hIdx * DIM;
  int n0 = nt * 64;
  size_t rowbase = (size_t)b * SEQ;
  const size_t dQ = (size_t)(ql - qh);      // hi->lo element offsets (uniform)
  const size_t dX = (size_t)(xl - xh);

  f32x4 accS[4][4];   // 4 q-row strips x 4 key strips (64 keys/wave)
  for (int i = 0; i < 4; ++i) for (int j = 0; j < 4; ++j)
    for (int z = 0; z < 4; ++z) accS[i][j][z] = 0.f;

  // stage this wave's 64 key rows (hi|lo interleaved 128B rows, XOR-8 slots)
  auto stageK = [&](int kt){
    int k0 = kt * 32;
    int base = (kt & 1)*32768 + w*4096;
    for (int rep = 0; rep < 8; ++rep){
      int id = rep*64 + l;                  // 0..511 chunk within wave's rows
      int row = id >> 3, s = id & 7, c = s ^ (row & 7);
      size_t hilo = (size_t)(c >> 2);
      GLOAD_LDS16(&xh[(rowbase + w*64 + row)*DIM + k0 + (c & 3)*8 + hilo*dX],
                  &lsh[base + id*8]);
    }
  };
  // q fragments direct from global into registers (identical across waves -> L2)
  auto loadQ = [&](int kt, half8* aH, half8* aL){
    int k0 = kt * 32;
    for (int i = 0; i < 4; ++i){
      size_t o = (rowbase + n0 + i*16 + lane16)*(size_t)qstride + qoff + k0 + quad*8;
      aH[i] = *(const half8*)&qh[o];
      aL[i] = *(const half8*)&qh[o + dQ];
    }
  };
  auto computeS = [&](int kt, half8* aH, half8* aL){
    int kbase = (kt & 1)*32768 + w*4096;
    for (int j = 0; j < 4; ++j){
      int r = j*16 + lane16;
      half8 bH = *(const half8*)&lsh[kbase + r*64 + (( quad    ^ (r & 7))*8)];
      half8 bL = *(const half8*)&lsh[kbase + r*64 + (((quad+4) ^ (r & 7))*8)];
      for (int i = 0; i < 4; ++i){
        accS[i][j] = __builtin_amdgcn_mfma_f32_16x16x32_f16(aL[i], bH, accS[i][j], 0, 0, 0);
        accS[i][j] = __builtin_amdgcn_mfma_f32_16x16x32_f16(aH[i], bL, accS[i][j], 0, 0, 0);
        accS[i][j] = __builtin_amdgcn_mfma_f32_16x16x32_f16(aH[i], bH, accS[i][j], 0, 0, 0);
      }
    }
  };

  // ---- Phase 1: scores; per-wave pipelines, no block barrier ----
  half8 aH0[4], aL0[4], aH1[4], aL1[4];
  stageK(0);
  asm volatile("" ::: "memory");            // pin: DMA issue before q loads
  loadQ(0, aH0, aL0);
  for (int kt = 0; kt < DIM/32; kt += 2){
    asm volatile("s_waitcnt vmcnt(8)" ::: "memory");   // own stage(kt) landed
    stageK(kt + 1);                                    // kt+1 <= 23 always
    asm volatile("" ::: "memory");
    loadQ(kt + 1, aH1, aL1);
    computeS(kt, aH0, aL0);
    asm volatile("s_waitcnt vmcnt(8)" ::: "memory");   // own stage(kt+1) landed
    if (kt + 2 < DIM/32){
      stageK(kt + 2);
      asm volatile("" ::: "memory");
      loadQ(kt + 2, aH0, aL0);
    }
    computeS(kt + 1, aH1, aL1);
  }
  __syncthreads();   // keys dead; repurpose pool (drains all outstanding loads)

  // stage xvT[b,h] rows (512 fp16 = 1024 B = one wave-instr per row)
  const int XVB = 34816;
  for (int it = 0; it < 8; ++it){
    int e = it*8 + w;
    GLOAD_LDS16(&xvT[((size_t)(b*NH + h)*HD + e)*SEQ + l*8], &lsh[XVB + e*SEQP]);
  }

  // ---- Phase 2: softmax ----
  float rmx[4][4];
  for (int i = 0; i < 4; ++i) for (int r = 0; r < 4; ++r){
    float m = accS[i][0][r];
    for (int j = 1; j < 4; ++j) m = fmaxf(m, accS[i][j][r]);
    for (int d = 1; d < 16; d <<= 1) m = fmaxf(m, __shfl_xor(m, d, 64));
    rmx[i][r] = m;
  }
  if (lane16 == 0)
    for (int i = 0; i < 4; ++i) for (int r = 0; r < 4; ++r)
      lStat[w*64 + i*16 + quad*4 + r] = rmx[i][r];
  __syncthreads();
  if (t < 64){
    float m = lStat[t];
    for (int ww = 1; ww < 8; ++ww) m = fmaxf(m, lStat[ww*64 + t]);
    lStat[512 + t] = m;
  }
  __syncthreads();
  float rsum[4][4];
  for (int i = 0; i < 4; ++i) for (int r = 0; r < 4; ++r){
    float g = lStat[512 + i*16 + quad*4 + r];
    float s = 0.f;
    for (int j = 0; j < 4; ++j){
      float p = __expf(accS[i][j][r] - g);
      s += p;
      lsh[(i*16 + quad*4 + r)*SEQP + (w*64 + j*16 + lane16)] = f2hu(p);
    }
    for (int d = 1; d < 16; d <<= 1) s += __shfl_xor(s, d, 64);
    rsum[i][r] = s;
  }
  if (lane16 == 0)
    for (int i = 0; i < 4; ++i) for (int r = 0; r < 4; ++r)
      lStat[w*64 + i*16 + quad*4 + r] = rsum[i][r];
  __syncthreads();
  if (t < 64){
    float s = lStat[t];
    for (int ww = 1; ww < 8; ++ww) s += lStat[ww*64 + t];
    lStat[576 + t] = s;
  }
  __syncthreads();   // P + xv + sums visible

  // ---- Phase 3: PV (wave w owns K-slice [64w, 64w+64)) ----
  f32x4 accO[4][4];
  for (int i = 0; i < 4; ++i) for (int j = 0; j < 4; ++j)
    for (int z = 0; z < 4; ++z) accO[i][j][z] = 0.f;
  for (int ks = 0; ks < 2; ++ks){
    int kb = w*64 + ks*32;
    half8 aP[4];
    for (int i = 0; i < 4; ++i)
      aP[i] = *(const half8*)&lsh[(i*16 + lane16)*SEQP + kb + quad*8];
    for (int j = 0; j < 4; ++j){
      half8 bV = *(const half8*)&lsh[XVB + (j*16 + lane16)*SEQP + kb + quad*8];
      for (int i = 0; i < 4; ++i)
        accO[i][j] = __builtin_amdgcn_mfma_f32_16x16x32_f16(aP[i], bV, accO[i][j], 0, 0, 0);
    }
  }
  __syncthreads();   // all reads of lP/lXv done before overwrite
  float* red = (float*)lsh;
  for (int i = 0; i < 4; ++i) for (int j = 0; j < 4; ++j) for (int r = 0; r < 4; ++r)
    red[w*4096 + (i*16 + quad*4 + r)*64 + (j*16 + lane16)] = accO[i][j][r];
  __syncthreads();
  for (int z = t; z < 4096; z += 512){
    int row = z >> 6, col = z & 63;
    float v = 0.f;
    for (int ww = 0; ww < 8; ++ww) v += red[ww*4096 + z];
    v /= lStat[576 + row];
    out[(rowbase + n0 + row)*DIM + h*HD + col] = v;
  }
}

// ---------------- launcher ----------------
extern "C" void kernel_launch(void* const* d_in, const int* in_sizes, int n_in,
                              void* d_out, int out_size, void* d_ws, size_t ws_size,
                              hipStream_t stream){
  const float* x = (const float*)d_in[0];
  const float* Q = (const float*)d_in[1];
  const float* V = (const float*)d_in[2];
  float* out = (float*)d_out;

  char* ws = (char*)d_ws;
  size_t off = 0;
  auto alloc = [&](size_t bytes) -> void* {
    void* p = ws + off;
    off += (bytes + 255) & ~(size_t)255;
    return p;
  };
  // NOTE: hi/lo pairs must stay contiguous (xl = xh + ROWS*DIM etc.) — the
  // staging code relies on constant hi->lo element offsets.
  unsigned short* xh  = (unsigned short*)alloc((size_t)ROWS*DIM*2);       // 25.2 MB
  unsigned short* xl  = (unsigned short*)alloc((size_t)ROWS*DIM*2);       // 25.2 MB
  unsigned short* qth = (unsigned short*)alloc((size_t)NH*DIM*DIM*2);     // 14.2 MB
  unsigned short* qtl = (unsigned short*)alloc((size_t)NH*DIM*DIM*2);     // 14.2 MB
  unsigned short* vt  = (unsigned short*)alloc((size_t)NH*HD*DIM*2);      //  1.2 MB
  unsigned short* xvT = (unsigned short*)alloc((size_t)B_SZ*NH*HD*SEQ*2); // 25.2 MB
  // fixed total ~105 MB

  // choose largest head-chunk whose q hi+lo buffers fit the workspace
  const int hcands[6] = {12, 6, 4, 3, 2, 1};
  int HC = 1;
  for (int i = 0; i < 6; ++i){
    size_t qb_bytes = ((size_t)ROWS * hcands[i] * DIM * 2 + 255) & ~(size_t)255;
    if (off + 2*qb_bytes <= ws_size){ HC = hcands[i]; break; }
  }
  unsigned short* qbh = (unsigned short*)alloc((size_t)ROWS*HC*DIM*2);
  unsigned short* qbl = (unsigned short*)alloc((size_t)ROWS*HC*DIM*2);

  int n4 = ROWS*DIM/4;
  k_split<<<n4/256, 256, 0, stream>>>(x, xh, xl, n4);
  k_transQ<<<dim3(DIM/32, DIM/32, NH), 256, 0, stream>>>(Q, qth, qtl);
  k_transV<<<dim3(DIM/32, HD/32, NH), 256, 0, stream>>>(V, vt);
  k_gemm_xv<<<dim3(4, B_SZ, NH), 256, 0, stream>>>(xh, vt, xvT);

  for (int h0 = 0; h0 < NH; h0 += HC){
    k_gemm_q<<<dim3(ROWS/128, HC*DIM/128), 256, 0, stream>>>(
        xh, xl, qth + (size_t)h0*DIM*DIM, qtl + (size_t)h0*DIM*DIM,
        qbh, qbl, HC*DIM);
    k_attn<<<dim3(8*HC, B_SZ), 512, 0, stream>>>(
        qbh, qbl, xh, xl, xvT, out, h0, HC);
  }
}

// Round 6
// 1545.349 us; speedup vs baseline: 1.2147x; 1.2147x over previous
//
#include <hip/hip_runtime.h>
#include <stdint.h>

// Problem constants
#define B_SZ 32
#define SEQ  512
#define DIM  768
#define NH   12
#define HD   64
#define ROWS (B_SZ*SEQ)   // 16384

typedef __attribute__((ext_vector_type(4))) float f32x4;
typedef __attribute__((ext_vector_type(8))) _Float16 half8;

// async global->LDS, 16B per lane; LDS dest = wave-uniform base + lane*16
#define GLOAD_LDS16(gaddr, laddr) \
  __builtin_amdgcn_global_load_lds((const __attribute__((address_space(1))) void*)(gaddr), \
                                   (__attribute__((address_space(3))) void*)(laddr), 16, 0, 0)

__device__ __forceinline__ unsigned short h2u(_Float16 h){
  union { _Float16 h; unsigned short u; } c; c.h = h; return c.u;
}
__device__ __forceinline__ unsigned short f2hu(float f){
  return h2u((_Float16)f);
}

// ---------------- prep kernels ----------------
__global__ void k_split(const float* __restrict__ x,
                        unsigned short* __restrict__ xh,
                        unsigned short* __restrict__ xl, int n4){
  int i = blockIdx.x * 256 + threadIdx.x;
  if (i >= n4) return;
  float4 v = ((const float4*)x)[i];
  ushort4 h, l;
  _Float16 t;
  t = (_Float16)v.x; h.x = h2u(t); l.x = f2hu(v.x - (float)t);
  t = (_Float16)v.y; h.y = h2u(t); l.y = f2hu(v.y - (float)t);
  t = (_Float16)v.z; h.z = h2u(t); l.z = f2hu(v.z - (float)t);
  t = (_Float16)v.w; h.w = h2u(t); l.w = f2hu(v.w - (float)t);
  ((ushort4*)xh)[i] = h;
  ((ushort4*)xl)[i] = l;
}

// QT[h][e][d] = split(Q[h][d][e]) — LDS-tiled transpose, both sides coalesced
__global__ __launch_bounds__(256) void k_transQ(const float* __restrict__ Q,
                         unsigned short* __restrict__ qth,
                         unsigned short* __restrict__ qtl){
  __shared__ float tile[32][33];
  int h = blockIdx.z;
  int d0 = blockIdx.x * 32;
  int e0 = blockIdx.y * 32;
  int tx = threadIdx.x & 31, ty = threadIdx.x >> 5;  // 32 x 8
  const float* Qh = Q + (size_t)h * DIM * DIM;
  for (int i = 0; i < 4; ++i)
    tile[ty + i*8][tx] = Qh[(size_t)(d0 + ty + i*8) * DIM + e0 + tx];
  __syncthreads();
  for (int i = 0; i < 4; ++i){
    float v = tile[tx][ty + i*8];
    size_t o = ((size_t)h * DIM + e0 + ty + i*8) * DIM + d0 + tx;
    _Float16 hi = (_Float16)v;
    qth[o] = h2u(hi);
    qtl[o] = f2hu(v - (float)hi);
  }
}

// Vt[h][e][d] = fp16(V[h][d][e]) — LDS-tiled transpose
__global__ __launch_bounds__(256) void k_transV(const float* __restrict__ V,
                         unsigned short* __restrict__ vt16){
  __shared__ float tile[32][33];
  int h = blockIdx.z;
  int d0 = blockIdx.x * 32;
  int e0 = blockIdx.y * 32;
  int tx = threadIdx.x & 31, ty = threadIdx.x >> 5;
  const float* Vh = V + (size_t)h * DIM * HD;
  for (int i = 0; i < 4; ++i)
    tile[ty + i*8][tx] = Vh[(size_t)(d0 + ty + i*8) * HD + e0 + tx];
  __syncthreads();
  for (int i = 0; i < 4; ++i)
    vt16[((size_t)h * HD + e0 + ty + i*8) * DIM + d0 + tx] = f2hu(tile[tx][ty + i*8]);
}

// ---------------- xV GEMM (round-0 proven: fp16 single-pass, BK=32) ----------------
__global__ __launch_bounds__(256) void k_gemm_xv(
    const unsigned short* __restrict__ xh,
    const unsigned short* __restrict__ vt16,
    unsigned short* __restrict__ xvT){
  __shared__ __align__(16) unsigned short lA[128*32];
  __shared__ __align__(16) unsigned short lB[64*32];
  __shared__ __align__(16) unsigned short lOut[64*128];
  int t = threadIdx.x, w = t >> 6, l = t & 63;
  int lane16 = l & 15, quad = l >> 4;
  int b = blockIdx.y, h = blockIdx.z;
  int m0 = blockIdx.x * 128;
  const unsigned short* vth = vt16 + (size_t)h * HD * DIM;
  f32x4 acc[2][4];
  for (int i = 0; i < 2; ++i) for (int j = 0; j < 4; ++j)
    for (int z = 0; z < 4; ++z) acc[i][j][z] = 0.f;

  for (int kt = 0; kt < DIM/32; ++kt){
    int k0 = kt * 32;
    __syncthreads();
    for (int rep = 0; rep < 2; ++rep){
      int id = t + rep * 256;              // 0..511
      int row = id >> 2, ko = (id & 3) * 8;
      GLOAD_LDS16(&xh[((size_t)(b*SEQ + m0 + row))*DIM + k0 + ko],
                  &lA[(rep*256 + w*64) * 8]);
    }
    { int row = t >> 2, ko = (t & 3) * 8;  // 64x32
      GLOAD_LDS16(&vth[(size_t)row*DIM + k0 + ko], &lB[(w*64) * 8]); }
    __syncthreads();
    half8 a[2];
    for (int i = 0; i < 2; ++i)
      a[i] = *(const half8*)&lA[(w*32 + i*16 + lane16)*32 + quad*8];
    for (int j = 0; j < 4; ++j){
      half8 bb = *(const half8*)&lB[(j*16 + lane16)*32 + quad*8];
      for (int i = 0; i < 2; ++i)
        acc[i][j] = __builtin_amdgcn_mfma_f32_16x16x32_f16(a[i], bb, acc[i][j], 0, 0, 0);
    }
  }
  __syncthreads();
  for (int i = 0; i < 2; ++i) for (int j = 0; j < 4; ++j) for (int r = 0; r < 4; ++r){
    int col = j*16 + lane16;
    int n  = w*32 + i*16 + quad*4 + r;
    lOut[col*128 + n] = f2hu(acc[i][j][r]);
  }
  __syncthreads();
  for (int rep = 0; rep < 4; ++rep){
    int id = t + rep*256;                  // 0..1023 int4s
    int e = id >> 4, no = (id & 15) * 8;
    *(int4*)&xvT[((size_t)(b*NH + h)*HD + e)*SEQ + m0 + no] = *(const int4*)&lOut[e*128 + no];
  }
}

// ---------------- q projection (r3-proven body + XCD-aware Mtile swizzle) ----------------
// q[bn][col] = sum_d x[bn][d] * Qflat[col][d], col in [0, ncols); Qflat = qth+h0 slab.
// grid (128 Mtiles, ncols/128 Ntiles), block 256, tile 128x128, BK=64, 64 KB LDS
// -> 2 blocks/CU. Single-buffered 2-barrier loop: structure ceiling ~40% MfmaUtil
// (r3 = 194.7us/launch). Measured-null grafts: dbuf (r2), 4-block occupancy (r4).
// Swizzle (T1): XCD k owns Mtiles [16k,16k+16) sweeping all Ntiles -> per-XCD hot
// set = A-stripe 6.3MB + one B-panel 0.39MB; B-slab fetched ~once (r3 FETCH was
// 152MB vs ~64MB ideal: x thrashed across XCDs).
__global__ __launch_bounds__(256, 2) void k_gemm_q(
    const unsigned short* __restrict__ xh, const unsigned short* __restrict__ xl,
    const unsigned short* __restrict__ bth, const unsigned short* __restrict__ btl,
    unsigned short* __restrict__ qh, unsigned short* __restrict__ ql, int ncols){
  __shared__ __align__(16) unsigned short lA[2][128*64];   // [hl] 32 KB
  __shared__ __align__(16) unsigned short lB[2][128*64];   // [hl] 32 KB
  int t = threadIdx.x, w = t >> 6, l = t & 63;
  int lane16 = l & 15, quad = l >> 4;
  // bijective XCD swizzle: n = y*128 + x (x fastest = dispatch order), xcd = n%8
  int nlin = blockIdx.y * gridDim.x + blockIdx.x;
  int xcd = nlin & 7, jj = nlin >> 3;
  int ntc = gridDim.y;                       // N-tile count (6*HC)
  int m0 = (xcd * 16 + jj / ntc) * 128;      // jj/ntc in [0,16)
  int n0 = (jj % ntc) * 128;
  int wr = (w >> 1) * 64, wc = (w & 1) * 64;
  f32x4 acc[4][4];
  for (int i = 0; i < 4; ++i) for (int j = 0; j < 4; ++j)
    for (int z = 0; z < 4; ++z) acc[i][j][z] = 0.f;

  for (int kt = 0; kt < DIM/64; ++kt){
    int k0 = kt * 64;
    __syncthreads();                       // previous compute's LDS reads done
    for (int rep = 0; rep < 4; ++rep){
      int id = t + rep * 256;              // 0..1023 (row, chunk)
      int row = id >> 3;
      int gc  = (id & 7) ^ (row & 7);      // fetch swizzled chunk into linear slot
      int lb  = (rep*256 + w*64) * 8;
      size_t gA = (size_t)(m0+row)*DIM + k0 + gc*8;
      size_t gB = (size_t)(n0+row)*DIM + k0 + gc*8;
      GLOAD_LDS16(&xh [gA], &lA[0][lb]);
      GLOAD_LDS16(&xl [gA], &lA[1][lb]);
      GLOAD_LDS16(&bth[gB], &lB[0][lb]);
      GLOAD_LDS16(&btl[gB], &lB[1][lb]);
    }
    __syncthreads();                       // drain staging
    for (int ks = 0; ks < 2; ++ks){
      int sw = ((ks*4 + quad) ^ (lane16 & 7)) * 8;   // swizzled chunk offset
      half8 aH[4], aL[4];
      for (int i = 0; i < 4; ++i){
        int r = wr + i*16 + lane16;
        aH[i] = *(const half8*)&lA[0][r*64 + sw];
        aL[i] = *(const half8*)&lA[1][r*64 + sw];
      }
      for (int j = 0; j < 4; ++j){
        int c = wc + j*16 + lane16;
        half8 bH = *(const half8*)&lB[0][c*64 + sw];
        half8 bL = *(const half8*)&lB[1][c*64 + sw];
        for (int i = 0; i < 4; ++i){
          acc[i][j] = __builtin_amdgcn_mfma_f32_16x16x32_f16(aL[i], bH, acc[i][j], 0, 0, 0);
          acc[i][j] = __builtin_amdgcn_mfma_f32_16x16x32_f16(aH[i], bL, acc[i][j], 0, 0, 0);
          acc[i][j] = __builtin_amdgcn_mfma_f32_16x16x32_f16(aH[i], bH, acc[i][j], 0, 0, 0);
        }
      }
    }
  }
  for (int i = 0; i < 4; ++i) for (int j = 0; j < 4; ++j) for (int r = 0; r < 4; ++r){
    int row = m0 + wr + i*16 + quad*4 + r;
    int col = n0 + wc + j*16 + lane16;
    float v = acc[i][j][r];
    _Float16 hh = (_Float16)v;
    size_t o = (size_t)row*ncols + col;
    qh[o] = h2u(hh);
    ql[o] = f2hu(v - (float)hh);
  }
}

// ---------------- fused attention (r3-proven body + XCD-aware b-grouping) ----------------
// grid (8*hc, 32). Swizzle (T1): XCD k owns batches [4k,4k+4); all 8*hc combos of
// one b run back-to-back on the same XCD -> key panel (1.5MB hi+lo) fetched ~once
// per XCD instead of 8x (r5 PMC: FETCH 447MB/launch = keys overfetched ~8x across
// XCD-private L2s). block 512 (8 waves). BM=64 q-rows, full 512 keys; split-fp16
// 3-pass scores; BK=32 block-wide dbuf staging (r3 body; barrier-free per-wave
// variant measured regressive in r5 - scattered q-loads overfetch).
// Phase-1 LDS rows = 128 B hi|lo interleaved, XOR-8 slots (conflict-free reads).
#define SEQP 520
__global__ __launch_bounds__(512) void k_attn(
    const unsigned short* __restrict__ qh, const unsigned short* __restrict__ ql,
    const unsigned short* __restrict__ xh, const unsigned short* __restrict__ xl,
    const unsigned short* __restrict__ xvT,
    float* __restrict__ out, int h0, int hc){
  __shared__ __align__(16) unsigned short lsh[73728];   // 144 KB
  __shared__ float lStat[8*64 + 64 + 64];               // 2.5 KB

  int t = threadIdx.x, w = t >> 6, l = t & 63;
  int lane16 = l & 15, quad = l >> 4;
  // bijective XCD swizzle: n = y*(8*hc) + x (dispatch order), xcd = n%8
  int nlin = blockIdx.y * gridDim.x + blockIdx.x;
  int xcd = nlin & 7, jj = nlin >> 3;
  int cpb = 8 * hc;                          // combos per batch
  int b = xcd * (B_SZ/8) + jj / cpb;         // jj/cpb in [0, B_SZ/8)
  int combo = jj % cpb;
  int hIdx = combo % hc, nt = combo / hc;
  int h = h0 + hIdx;
  int qstride = hc * DIM;
  size_t qoff = (size_t)hIdx * DIM;
  int n0 = nt * 64;
  size_t rowbase = (size_t)b * SEQ;
  const size_t dQ = (size_t)(ql - qh);      // hi->lo element offsets (uniform)
  const size_t dX = (size_t)(xl - xh);

  f32x4 accS[4][4];   // 4 q-row strips x 4 key strips (64 keys/wave)
  for (int i = 0; i < 4; ++i) for (int j = 0; j < 4; ++j)
    for (int z = 0; z < 4; ++z) accS[i][j][z] = 0.f;

  auto stage = [&](int kt){
    int k0 = kt * 32, bb = kt & 1;
    int qb = 65536 + bb*4096;
    { // q: 64 rows x 8 slots = 512 chunks, 1 per thread
      int row = t >> 3, s = t & 7, c = s ^ (row & 7);
      size_t hilo = (size_t)(c >> 2);
      GLOAD_LDS16(&qh[(rowbase + n0 + row)*qstride + qoff + k0 + (c & 3)*8 + hilo*dQ],
                  &lsh[qb + t*8]);
    }
    int kb = bb*32768;
    for (int rep = 0; rep < 8; ++rep){      // keys: 512 rows x 8 slots = 4096 chunks
      int id = t + rep * 512;
      int row = id >> 3, s = id & 7, c = s ^ (row & 7);
      size_t hilo = (size_t)(c >> 2);
      GLOAD_LDS16(&xh[(rowbase + row)*DIM + k0 + (c & 3)*8 + hilo*dX],
                  &lsh[kb + id*8]);
    }
  };

  // ---- Phase 1: scores, double-buffered, 3-pass split ----
  stage(0);
  for (int kt = 0; kt < DIM/32; ++kt){
    __syncthreads();                 // drains staging of buffer kt&1
    if (kt + 1 < DIM/32) stage(kt + 1);   // prefetch in flight during compute
    int bb = kt & 1;
    int qb = 65536 + bb*4096, kb = bb*32768;
    half8 aH[4], aL[4];
    for (int i = 0; i < 4; ++i){
      int r = i*16 + lane16;
      aH[i] = *(const half8*)&lsh[qb + r*64 + (( quad    ^ (r & 7))*8)];
      aL[i] = *(const half8*)&lsh[qb + r*64 + (((quad+4) ^ (r & 7))*8)];
    }
    for (int j = 0; j < 4; ++j){
      int c = w*64 + j*16 + lane16;
      half8 bH = *(const half8*)&lsh[kb + c*64 + (( quad    ^ (c & 7))*8)];
      half8 bL = *(const half8*)&lsh[kb + c*64 + (((quad+4) ^ (c & 7))*8)];
      for (int i = 0; i < 4; ++i){
        accS[i][j] = __builtin_amdgcn_mfma_f32_16x16x32_f16(aL[i], bH, accS[i][j], 0, 0, 0);
        accS[i][j] = __builtin_amdgcn_mfma_f32_16x16x32_f16(aH[i], bL, accS[i][j], 0, 0, 0);
        accS[i][j] = __builtin_amdgcn_mfma_f32_16x16x32_f16(aH[i], bH, accS[i][j], 0, 0, 0);
      }
    }
  }
  __syncthreads();   // keys/q dead; repurpose pool

  // stage xvT[b,h] rows (512 fp16 = 1024 B = one wave-instr per row)
  const int XVB = 34816;
  for (int it = 0; it < 8; ++it){
    int e = it*8 + w;
    GLOAD_LDS16(&xvT[((size_t)(b*NH + h)*HD + e)*SEQ + l*8], &lsh[XVB + e*SEQP]);
  }

  // ---- Phase 2: softmax ----
  float rmx[4][4];
  for (int i = 0; i < 4; ++i) for (int r = 0; r < 4; ++r){
    float m = accS[i][0][r];
    for (int j = 1; j < 4; ++j) m = fmaxf(m, accS[i][j][r]);
    for (int d = 1; d < 16; d <<= 1) m = fmaxf(m, __shfl_xor(m, d, 64));
    rmx[i][r] = m;
  }
  if (lane16 == 0)
    for (int i = 0; i < 4; ++i) for (int r = 0; r < 4; ++r)
      lStat[w*64 + i*16 + quad*4 + r] = rmx[i][r];
  __syncthreads();
  if (t < 64){
    float m = lStat[t];
    for (int ww = 1; ww < 8; ++ww) m = fmaxf(m, lStat[ww*64 + t]);
    lStat[512 + t] = m;
  }
  __syncthreads();
  float rsum[4][4];
  for (int i = 0; i < 4; ++i) for (int r = 0; r < 4; ++r){
    float g = lStat[512 + i*16 + quad*4 + r];
    float s = 0.f;
    for (int j = 0; j < 4; ++j){
      float p = __expf(accS[i][j][r] - g);
      s += p;
      lsh[(i*16 + quad*4 + r)*SEQP + (w*64 + j*16 + lane16)] = f2hu(p);
    }
    for (int d = 1; d < 16; d <<= 1) s += __shfl_xor(s, d, 64);
    rsum[i][r] = s;
  }
  if (lane16 == 0)
    for (int i = 0; i < 4; ++i) for (int r = 0; r < 4; ++r)
      lStat[w*64 + i*16 + quad*4 + r] = rsum[i][r];
  __syncthreads();
  if (t < 64){
    float s = lStat[t];
    for (int ww = 1; ww < 8; ++ww) s += lStat[ww*64 + t];
    lStat[576 + t] = s;
  }
  __syncthreads();   // P + xv + sums visible

  // ---- Phase 3: PV (wave w owns K-slice [64w, 64w+64)) ----
  f32x4 accO[4][4];
  for (int i = 0; i < 4; ++i) for (int j = 0; j < 4; ++j)
    for (int z = 0; z < 4; ++z) accO[i][j][z] = 0.f;
  for (int ks = 0; ks < 2; ++ks){
    int kb = w*64 + ks*32;
    half8 aP[4];
    for (int i = 0; i < 4; ++i)
      aP[i] = *(const half8*)&lsh[(i*16 + lane16)*SEQP + kb + quad*8];
    for (int j = 0; j < 4; ++j){
      half8 bV = *(const half8*)&lsh[XVB + (j*16 + lane16)*SEQP + kb + quad*8];
      for (int i = 0; i < 4; ++i)
        accO[i][j] = __builtin_amdgcn_mfma_f32_16x16x32_f16(aP[i], bV, accO[i][j], 0, 0, 0);
    }
  }
  __syncthreads();   // all reads of lP/lXv done before overwrite
  float* red = (float*)lsh;
  for (int i = 0; i < 4; ++i) for (int j = 0; j < 4; ++j) for (int r = 0; r < 4; ++r)
    red[w*4096 + (i*16 + quad*4 + r)*64 + (j*16 + lane16)] = accO[i][j][r];
  __syncthreads();
  for (int z = t; z < 4096; z += 512){
    int row = z >> 6, col = z & 63;
    float v = 0.f;
    for (int ww = 0; ww < 8; ++ww) v += red[ww*4096 + z];
    v /= lStat[576 + row];
    out[(rowbase + n0 + row)*DIM + h*HD + col] = v;
  }
}

// ---------------- launcher ----------------
extern "C" void kernel_launch(void* const* d_in, const int* in_sizes, int n_in,
                              void* d_out, int out_size, void* d_ws, size_t ws_size,
                              hipStream_t stream){
  const float* x = (const float*)d_in[0];
  const float* Q = (const float*)d_in[1];
  const float* V = (const float*)d_in[2];
  float* out = (float*)d_out;

  char* ws = (char*)d_ws;
  size_t off = 0;
  auto alloc = [&](size_t bytes) -> void* {
    void* p = ws + off;
    off += (bytes + 255) & ~(size_t)255;
    return p;
  };
  // NOTE: hi/lo pairs must stay contiguous (xl = xh + ROWS*DIM etc.) — the
  // staging code relies on constant hi->lo element offsets.
  unsigned short* xh  = (unsigned short*)alloc((size_t)ROWS*DIM*2);       // 25.2 MB
  unsigned short* xl  = (unsigned short*)alloc((size_t)ROWS*DIM*2);       // 25.2 MB
  unsigned short* qth = (unsigned short*)alloc((size_t)NH*DIM*DIM*2);     // 14.2 MB
  unsigned short* qtl = (unsigned short*)alloc((size_t)NH*DIM*DIM*2);     // 14.2 MB
  unsigned short* vt  = (unsigned short*)alloc((size_t)NH*HD*DIM*2);      //  1.2 MB
  unsigned short* xvT = (unsigned short*)alloc((size_t)B_SZ*NH*HD*SEQ*2); // 25.2 MB
  // fixed total ~105 MB

  // choose largest head-chunk whose q hi+lo buffers fit the workspace
  const int hcands[6] = {12, 6, 4, 3, 2, 1};
  int HC = 1;
  for (int i = 0; i < 6; ++i){
    size_t qb_bytes = ((size_t)ROWS * hcands[i] * DIM * 2 + 255) & ~(size_t)255;
    if (off + 2*qb_bytes <= ws_size){ HC = hcands[i]; break; }
  }
  unsigned short* qbh = (unsigned short*)alloc((size_t)ROWS*HC*DIM*2);
  unsigned short* qbl = (unsigned short*)alloc((size_t)ROWS*HC*DIM*2);

  int n4 = ROWS*DIM/4;
  k_split<<<n4/256, 256, 0, stream>>>(x, xh, xl, n4);
  k_transQ<<<dim3(DIM/32, DIM/32, NH), 256, 0, stream>>>(Q, qth, qtl);
  k_transV<<<dim3(DIM/32, HD/32, NH), 256, 0, stream>>>(V, vt);
  k_gemm_xv<<<dim3(4, B_SZ, NH), 256, 0, stream>>>(xh, vt, xvT);

  for (int h0 = 0; h0 < NH; h0 += HC){
    k_gemm_q<<<dim3(ROWS/128, HC*DIM/128), 256, 0, stream>>>(
        xh, xl, qth + (size_t)h0*DIM*DIM, qtl + (size_t)h0*DIM*DIM,
        qbh, qbl, HC*DIM);
    k_attn<<<dim3(8*HC, B_SZ), 512, 0, stream>>>(
        qbh, qbl, xh, xl, xvT, out, h0, HC);
  }
}